// Round 13
// baseline (317.634 us; speedup 1.0000x reference)
//
#include <hip/hip_runtime.h>

#define KK  128   // samples per ray
#define RPW 8     // rays per wave (wave-private)
#define TPB 128   // 2 independent waves per block; 8 KB LDS/block -> ~16 blocks/CU

// borders = [z0, 0.5f*(z[i]+z[i-1]), z127]; expression text identical to R8-R12
__device__ __forceinline__ float blerp(const float* __restrict__ Z, int c, float t)
{
    float zc = Z[c];
    float zm = Z[c > 0 ? c - 1 : 0];
    float zp = Z[c < KK - 1 ? c + 1 : KK - 1];
    float left  = (c == 0)      ? zc : 0.5f * (zc + zm);
    float right = (c == KK - 1) ? zc : 0.5f * (zp + zc);
    return left * (1.0f - t) + right * t;
}

__global__ __launch_bounds__(TPB, 8)
void nerf_sample_kernel(const float* __restrict__ Wg,
                        const float* __restrict__ Zg,
                        const float* __restrict__ Ug,
                        const float* __restrict__ Tg,
                        float* __restrict__ Og)
{
    // wave-private 4KB cdf region; NO __syncthreads (single-wave DS ordering)
    __shared__ float S[2 * RPW * KK];   // 8 KB/block
    const int lane = threadIdx.x & 63;
    const int wvid = threadIdx.x >> 6;
    float* SW = S + wvid * (RPW * KK);

    const int r   = lane >> 3;          // ray slot 0..7 (same in build & search)
    const int h   = lane & 7;           // sub-lane: owns elements [16h, 16h+16)
    const int swz = r << 3;             // 8-float-block XOR swizzle across rows
    float* Srow = SW + r * KK;

    const size_t grp   = (size_t)blockIdx.x * 2 + wvid;
    const size_t gbase = grp * (RPW * KK);
    const size_t rbase = gbase + (size_t)r * KK;   // this lane's ray

    // ---- u/t prefetch (phase C), issued first to overlap the whole build ----
    float4 U4[4], T4[4];
    #pragma unroll
    for (int j = 0; j < 4; ++j) {
        U4[j] = *(const float4*)(Ug + rbase + 32 * j + 4 * h);
        T4[j] = *(const float4*)(Tg + rbase + 32 * j + 4 * h);
    }

    // ---- load own 16 weights; w' = fl32(w + 1e-5f) ----
    float x[16];
    {
        const float* wp = Wg + rbase + 16 * h;
        #pragma unroll
        for (int e = 0; e < 4; ++e) {
            float4 v = *(const float4*)(wp + 4 * e);
            x[4*e+0] = v.x + 1e-5f;
            x[4*e+1] = v.y + 1e-5f;
            x[4*e+2] = v.z + 1e-5f;
            x[4*e+3] = v.w + 1e-5f;
        }
    }

    // ---- tot: npyv model, EXACT R8 grouping. Lane h holds 16-chunk V_h.
    // acc_k = V_k + V_{k+4} (xor4); (acc0+acc1) (xor1); +(acc2+acc3) (xor2);
    // swapped-operand cases are commutative -> bitwise equal.
    float tot;
    {
        float Cc[16];
        #pragma unroll
        for (int c = 0; c < 16; ++c) {
            float a = x[c] + __shfl_xor(x[c], 4);
            float b = a    + __shfl_xor(a, 1);
            Cc[c]   = b    + __shfl_xor(b, 2);
        }
        float Uu[8];
        #pragma unroll
        for (int c = 0; c < 8; ++c) Uu[c] = Cc[c] + Cc[c + 8];
        float Vv[4];
        #pragma unroll
        for (int c = 0; c < 4; ++c) Vv[c] = Uu[c] + Uu[c + 4];
        tot = (Vv[0] + Vv[2]) + (Vv[1] + Vv[3]);
    }

    // ---- pdf: IEEE f32 divide ----
    #pragma unroll
    for (int j = 0; j < 16; ++j) x[j] = x[j] / tot;

    // ---- BK scan: levels 1-4 lane-local ----
    #pragma unroll
    for (int m = 0; m < 8; ++m) x[2*m+1] = x[2*m+1] + x[2*m];
    #pragma unroll
    for (int m = 0; m < 4; ++m) x[4*m+3] = x[4*m+3] + x[4*m+1];
    #pragma unroll
    for (int m = 0; m < 2; ++m) x[8*m+7] = x[8*m+7] + x[8*m+3];
    x[15] = x[15] + x[7];

    // ---- levels 5-7 + down 6/5 cross-lane; per-lane prefix P ----
    {
        float s    = x[15];                  // segment sum s_h
        float sx1  = __shfl_xor(s, 1);       // s_{h^1}
        float t1   = s + sx1;                // pair sum (comm-exact)
        float t1x2 = __shfl_xor(t1, 2);
        float t2   = t1 + t1x2;              // quad sum
        float t2x4 = __shfl_xor(t2, 4);
        float c95  = t1x2 + t2x4;            // cdf[95] as seen by lanes 6,7

        // finalize x[15] = cdf[16h+15] (each grouping matches BK level order)
        float xf =
            (h == 0) ? s :
            (h == 1) ? t1 :
            (h == 2) ? s + t1x2 :
            (h == 3) ? t2 :
            (h == 4) ? s + t2x4 :
            (h == 5) ? t1 + t2x4 :
            (h == 6) ? s + c95 :
                       t2 + t2x4;
        x[15] = xf;

        // P = cdf[16h-1]; 0 for h=0 (x+0.0f exact, all values > 0)
        float P =
            (h == 0) ? 0.0f :
            (h == 1) ? sx1 :
            (h == 2) ? t1x2 :
            (h == 3) ? sx1 + t1x2 :
            (h == 4) ? t2x4 :
            (h == 5) ? sx1 + t2x4 :
            (h == 6) ? c95 :
                       sx1 + c95;

        // ---- local down-sweep (levels 4..1) with P injected ----
        x[7]  = x[7]  + P;                                        // d4
        x[3]  = x[3]  + P;  x[11] = x[11] + x[7];                 // d3
        x[1]  = x[1]  + P;  x[5]  = x[5]  + x[3];                 // d2
        x[9]  = x[9]  + x[7];  x[13] = x[13] + x[11];
        x[0]  = x[0]  + P;                                        // d1
        #pragma unroll
        for (int m = 1; m < 8; ++m) x[2*m] = x[2*m] + x[2*m-1];
    }

    // ---- write cdf to wave-private LDS (8-float-block XOR swizzle) ----
    #pragma unroll
    for (int e = 0; e < 4; ++e)
        *(float4*)(Srow + ((16*h + 4*e) ^ swz)) =
            make_float4(x[4*e+0], x[4*e+1], x[4*e+2], x[4*e+3]);

    // wave-level fence: stop compiler moving search reads above the writes
    __builtin_amdgcn_sched_barrier(0);
    __builtin_amdgcn_wave_barrier();
    __builtin_amdgcn_sched_barrier(0);

    // ---- phase C: 16 hedged searches per lane (own ray), 2 halves of 8 ----
    const float EPSL = 1.0f - 1.8e-7f;
    const float EPSH = 1.0f + 1.8e-7f;
    const float* crow = Srow;
    const int    csw  = swz;
    const float* Z    = Zg + rbase;

    #pragma unroll
    for (int half = 0; half < 2; ++half) {
        const int j0 = 2 * half, j1 = 2 * half + 1;
        float uu[8] = {U4[j0].x, U4[j0].y, U4[j0].z, U4[j0].w,
                       U4[j1].x, U4[j1].y, U4[j1].z, U4[j1].w};
        float tv[8] = {T4[j0].x, T4[j0].y, T4[j0].z, T4[j0].w,
                       T4[j1].x, T4[j1].y, T4[j1].z, T4[j1].w};
        float ul[8], uh[8];
        int hh[8];
        #pragma unroll
        for (int i = 0; i < 8; ++i) {
            ul[i] = uu[i] * EPSL;
            uh[i] = uu[i] * EPSH;
            hh[i] = 0;
        }
        #pragma unroll
        for (int s = 64; s >= 1; s >>= 1) {   // 8 independent chains (ILP)
            #pragma unroll
            for (int i = 0; i < 8; ++i) {
                float b = crow[(hh[i] + s - 1) ^ csw];
                if (b <= uh[i]) hh[i] += s;
            }
        }

        float res[8];
        #pragma unroll
        for (int i = 0; i < 8; ++i) {
            const int hi = hh[i];                 // #{cdf<=uh} capped at 127
            int li = hi;                          // l differs only in hedge window
            while (li > 0 && crow[(li - 1) ^ csw] > ul[i]) --li;
            res[i] = (li == hi) ? blerp(Z, hi, tv[i])
                                : 0.5f * (blerp(Z, li, tv[i]) + blerp(Z, hi, tv[i]));
        }
        *(float4*)(Og + rbase + 32 * j0 + 4 * h) = make_float4(res[0], res[1], res[2], res[3]);
        *(float4*)(Og + rbase + 32 * j1 + 4 * h) = make_float4(res[4], res[5], res[6], res[7]);
    }
}

extern "C" void kernel_launch(void* const* d_in, const int* in_sizes, int n_in,
                              void* d_out, int out_size, void* d_ws, size_t ws_size,
                              hipStream_t stream)
{
    // inputs: 0=rays (unused), 1=weights, 2=z_samp, 3=u, 4=interval_interp
    const float* Wg = (const float*)d_in[1];
    const float* Zg = (const float*)d_in[2];
    const float* Ug = (const float*)d_in[3];
    const float* Tg = (const float*)d_in[4];
    float* Og = (float*)d_out;

    const int nrays  = in_sizes[1] / KK;        // 262144
    const int blocks = nrays / (2 * RPW);       // 16384 (2 waves x 8 rays)

    nerf_sample_kernel<<<dim3(blocks), dim3(TPB), 0, stream>>>(Wg, Zg, Ug, Tg, Og);
}

// Round 14
// 168.383 us; speedup vs baseline: 1.8864x; 1.8864x over previous
//
#include <hip/hip_runtime.h>

#define KK  128   // samples per ray
#define RPW 8     // rays per wave (wave-private)
#define TPB 128   // 2 independent waves per block; 8 KB LDS/block -> ~16 blocks/CU

// borders = [z0, 0.5f*(z[i]+z[i-1]), z127]; expression text identical to R8-R13
__device__ __forceinline__ float blerp(const float* __restrict__ Z, int c, float t)
{
    float zc = Z[c];
    float zm = Z[c > 0 ? c - 1 : 0];
    float zp = Z[c < KK - 1 ? c + 1 : KK - 1];
    float left  = (c == 0)      ? zc : 0.5f * (zc + zm);
    float right = (c == KK - 1) ? zc : 0.5f * (zp + zc);
    return left * (1.0f - t) + right * t;
}

__global__ __launch_bounds__(TPB, 8)
void nerf_sample_kernel(const float* __restrict__ Wg,
                        const float* __restrict__ Zg,
                        const float* __restrict__ Ug,
                        const float* __restrict__ Tg,
                        float* __restrict__ Og)
{
    // wave-private 4KB cdf region; NO __syncthreads (single-wave DS ordering)
    __shared__ float S[2 * RPW * KK];   // 8 KB/block
    const int lane = threadIdx.x & 63;
    const int wvid = threadIdx.x >> 6;
    float* SW = S + wvid * (RPW * KK);

    const int r   = lane >> 3;          // build: ray slot 0..7
    const int h   = lane & 7;           // build: owns elements [16h, 16h+16)
    const int swz = r << 3;             // 8-float-block XOR swizzle across rows
    float* Srow = SW + r * KK;

    const size_t grp   = (size_t)blockIdx.x * 2 + wvid;
    const size_t gbase = grp * (RPW * KK);
    const size_t rbase = gbase + (size_t)r * KK;

    // ---- phase-C it=0 prefetch: WAVE-LINEAR 1KB loads (lane -> flat 4*lane) ----
    float4 cu = *(const float4*)(Ug + gbase + 4 * lane);
    float4 ct = *(const float4*)(Tg + gbase + 4 * lane);

    // ---- load own 16 weights; w' = fl32(w + 1e-5f) ----
    float x[16];
    {
        const float* wp = Wg + rbase + 16 * h;
        #pragma unroll
        for (int e = 0; e < 4; ++e) {
            float4 v = *(const float4*)(wp + 4 * e);
            x[4*e+0] = v.x + 1e-5f;
            x[4*e+1] = v.y + 1e-5f;
            x[4*e+2] = v.z + 1e-5f;
            x[4*e+3] = v.w + 1e-5f;
        }
    }

    // ---- tot: npyv model, EXACT R8 grouping (R13 verbatim) ----
    float tot;
    {
        float Cc[16];
        #pragma unroll
        for (int c = 0; c < 16; ++c) {
            float a = x[c] + __shfl_xor(x[c], 4);
            float b = a    + __shfl_xor(a, 1);
            Cc[c]   = b    + __shfl_xor(b, 2);
        }
        float Uu[8];
        #pragma unroll
        for (int c = 0; c < 8; ++c) Uu[c] = Cc[c] + Cc[c + 8];
        float Vv[4];
        #pragma unroll
        for (int c = 0; c < 4; ++c) Vv[c] = Uu[c] + Uu[c + 4];
        tot = (Vv[0] + Vv[2]) + (Vv[1] + Vv[3]);
    }

    // ---- pdf: IEEE f32 divide ----
    #pragma unroll
    for (int j = 0; j < 16; ++j) x[j] = x[j] / tot;

    // ---- BK scan levels 1-4 lane-local (R13 verbatim) ----
    #pragma unroll
    for (int m = 0; m < 8; ++m) x[2*m+1] = x[2*m+1] + x[2*m];
    #pragma unroll
    for (int m = 0; m < 4; ++m) x[4*m+3] = x[4*m+3] + x[4*m+1];
    #pragma unroll
    for (int m = 0; m < 2; ++m) x[8*m+7] = x[8*m+7] + x[8*m+3];
    x[15] = x[15] + x[7];

    // ---- cross-lane levels + prefix P (R13 verbatim) ----
    {
        float s    = x[15];
        float sx1  = __shfl_xor(s, 1);
        float t1   = s + sx1;
        float t1x2 = __shfl_xor(t1, 2);
        float t2   = t1 + t1x2;
        float t2x4 = __shfl_xor(t2, 4);
        float c95  = t1x2 + t2x4;

        float xf =
            (h == 0) ? s :
            (h == 1) ? t1 :
            (h == 2) ? s + t1x2 :
            (h == 3) ? t2 :
            (h == 4) ? s + t2x4 :
            (h == 5) ? t1 + t2x4 :
            (h == 6) ? s + c95 :
                       t2 + t2x4;
        x[15] = xf;

        float P =
            (h == 0) ? 0.0f :
            (h == 1) ? sx1 :
            (h == 2) ? t1x2 :
            (h == 3) ? sx1 + t1x2 :
            (h == 4) ? t2x4 :
            (h == 5) ? sx1 + t2x4 :
            (h == 6) ? c95 :
                       sx1 + c95;

        x[7]  = x[7]  + P;
        x[3]  = x[3]  + P;  x[11] = x[11] + x[7];
        x[1]  = x[1]  + P;  x[5]  = x[5]  + x[3];
        x[9]  = x[9]  + x[7];  x[13] = x[13] + x[11];
        x[0]  = x[0]  + P;
        #pragma unroll
        for (int m = 1; m < 8; ++m) x[2*m] = x[2*m] + x[2*m-1];
    }

    // ---- write cdf to wave-private LDS (swizzled) ----
    #pragma unroll
    for (int e = 0; e < 4; ++e)
        *(float4*)(Srow + ((16*h + 4*e) ^ swz)) =
            make_float4(x[4*e+0], x[4*e+1], x[4*e+2], x[4*e+3]);

    // wave-level fence: stop compiler moving search reads above the writes
    __builtin_amdgcn_sched_barrier(0);
    __builtin_amdgcn_wave_barrier();
    __builtin_amdgcn_sched_barrier(0);

    // ---- phase C: it serves rays {2it, 2it+1}; lane handles flat 4*lane ----
    // -> every U/T load and O store is 1KB wave-linear (R12's clean-write pattern)
    const float EPSL = 1.0f - 1.8e-7f;
    const float EPSH = 1.0f + 1.8e-7f;
    const int rhalf = lane >> 5;           // which of the 2 rays this iteration

    for (int it = 0; it < 4; ++it) {
        float4 uu4 = cu, tt4 = ct;
        if (it < 3) {
            cu = *(const float4*)(Ug + gbase + (it + 1) * 256 + 4 * lane);
            ct = *(const float4*)(Tg + gbase + (it + 1) * 256 + 4 * lane);
        }

        const int rr = 2 * it + rhalf;
        const float* crow = SW + rr * KK;
        const int csw = rr << 3;
        const float* Z = Zg + gbase + (size_t)rr * KK;

        float uu[4] = {uu4.x, uu4.y, uu4.z, uu4.w};
        float tv[4] = {tt4.x, tt4.y, tt4.z, tt4.w};
        float ul[4], uh[4];
        int hh[4];
        #pragma unroll
        for (int i = 0; i < 4; ++i) {
            ul[i] = uu[i] * EPSL;
            uh[i] = uu[i] * EPSH;
            hh[i] = 0;
        }
        #pragma unroll
        for (int s = 64; s >= 1; s >>= 1) {   // early steps broadcast (same addr)
            #pragma unroll
            for (int i = 0; i < 4; ++i) {
                float b = crow[(hh[i] + s - 1) ^ csw];
                if (b <= uh[i]) hh[i] += s;
            }
        }

        float res[4];
        #pragma unroll
        for (int i = 0; i < 4; ++i) {
            const int hi = hh[i];                 // #{cdf<=uh} capped at 127
            int li = hi;                          // l differs only in hedge window
            while (li > 0 && crow[(li - 1) ^ csw] > ul[i]) --li;
            res[i] = (li == hi) ? blerp(Z, hi, tv[i])
                                : 0.5f * (blerp(Z, li, tv[i]) + blerp(Z, hi, tv[i]));
        }
        *(float4*)(Og + gbase + it * 256 + 4 * lane) =
            make_float4(res[0], res[1], res[2], res[3]);
    }
}

extern "C" void kernel_launch(void* const* d_in, const int* in_sizes, int n_in,
                              void* d_out, int out_size, void* d_ws, size_t ws_size,
                              hipStream_t stream)
{
    // inputs: 0=rays (unused), 1=weights, 2=z_samp, 3=u, 4=interval_interp
    const float* Wg = (const float*)d_in[1];
    const float* Zg = (const float*)d_in[2];
    const float* Ug = (const float*)d_in[3];
    const float* Tg = (const float*)d_in[4];
    float* Og = (float*)d_out;

    const int nrays  = in_sizes[1] / KK;        // 262144
    const int blocks = nrays / (2 * RPW);       // 16384 (2 waves x 8 rays)

    nerf_sample_kernel<<<dim3(blocks), dim3(TPB), 0, stream>>>(Wg, Zg, Ug, Tg, Og);
}